// Round 18
// baseline (332.410 us; speedup 1.0000x reference)
//
#include <hip/hip_runtime.h>
#include <hip/hip_bf16.h>
#include <cstdint>

// SemlaLayer fused forward for MI355X (gfx950).
// R18: KV=64 (4 k-tiles, 14 barriers vs 26). Spill-free midpoint between
// R9 (KV=32, 270us) and R15 (KV=128, spilled): acc regs ~190 < 256 unified.
// W2 tile-8 streamed from L2 on wave 7 (saves 32-reg w2r2 allocation).
// lds_barrier (lgkmcnt-only) + setprio kept from R17.

typedef __bf16 bf16x8_t __attribute__((ext_vector_type(8)));
typedef float  f32x4_t  __attribute__((ext_vector_type(4)));

#define SP 76   // sS pitch in floats
#define KV 64   // k-tile rows

__device__ __forceinline__ int swzX(int row, int col) {   // pitch 192
    return row * 192 + (col ^ ((row & 7) << 3));
}
__device__ __forceinline__ int swzH(int row, int col) {   // pitch 256
    return (row << 8) + (col ^ ((row & 7) << 3));
}

__device__ __forceinline__ bf16x8_t cvt8(f32x4_t a, f32x4_t b) {
    bf16x8_t r;
    r[0] = (__bf16)a.x; r[1] = (__bf16)a.y; r[2] = (__bf16)a.z; r[3] = (__bf16)a.w;
    r[4] = (__bf16)b.x; r[5] = (__bf16)b.y; r[6] = (__bf16)b.z; r[7] = (__bf16)b.w;
    return r;
}

__device__ __forceinline__ void lds_barrier() {
    asm volatile("s_waitcnt lgkmcnt(0)" ::: "memory");
    __builtin_amdgcn_s_barrier();
    asm volatile("" ::: "memory");
}

// ---------------- pre-kernel ----------------
// blocks 0..255  : 4 (b,n) rows each -> kmsg, pTE, pTF (transposed), qc
// blocks 256..267: W1bf (256x192, W1 cols 64..255)
// blocks 268..276: W2bf (144x256, rows reordered: edge(72..135)|logit(0..71)|pad)
__global__ __launch_bounds__(256) void semla_pre(
    const float* __restrict__ invs, const float* __restrict__ equis,
    const float* __restrict__ Wq, const float* __restrict__ bq,
    const float* __restrict__ Wk, const float* __restrict__ bk,
    const float* __restrict__ Wc, const float* __restrict__ Wi, const float* __restrict__ bi,
    const float* __restrict__ W1, const float* __restrict__ W2,
    __bf16* __restrict__ W1bf, __bf16* __restrict__ W2bf,
    float* __restrict__ qc, float* __restrict__ kmsg,
    float* __restrict__ pTE, float* __restrict__ pTF)
{
    const int blk = blockIdx.x, tid = threadIdx.x;
    if (blk < 256) {
        const int r0 = blk * 4;
        __shared__ __align__(16) float sInv4[4][256];
        __shared__ __align__(16) float sEqu4[4][192];
        __shared__ __align__(16) float sQm4[4][64];
        #pragma unroll
        for (int j = 0; j < 4; ++j) {
            sInv4[j][tid] = invs[(size_t)(r0 + j) * 256 + tid];
            if (tid < 192) sEqu4[j][tid] = equis[(size_t)(r0 + j) * 192 + tid];
        }
        __syncthreads();
        {   // projF = invs @ Wi.T + bi  -> pTF[b][f][n]
            float acc[4] = {0.f, 0.f, 0.f, 0.f};
            const float* w = &Wi[tid * 256];
            for (int i = 0; i < 256; i += 4) {
                f32x4_t ww = *(const f32x4_t*)&w[i];
                #pragma unroll
                for (int j = 0; j < 4; ++j) {
                    const float* x = &sInv4[j][i];
                    acc[j] += ww.x * x[0] + ww.y * x[1] + ww.z * x[2] + ww.w * x[3];
                }
            }
            const float bb = bi[tid];
            #pragma unroll
            for (int j = 0; j < 4; ++j) {
                const int bb_ = (r0 + j) >> 8, nl = (r0 + j) & 255;
                pTF[((size_t)bb_ * 256 + tid) * 256 + nl] = acc[j] + bb;
            }
        }
        if (tid < 128) {   // qmsg (to LDS) / kmsg (to global)
            const int d = tid & 63;
            const float* w = (tid < 64) ? &Wq[d * 256] : &Wk[d * 256];
            float acc[4] = {0.f, 0.f, 0.f, 0.f};
            for (int i = 0; i < 256; i += 4) {
                f32x4_t ww = *(const f32x4_t*)&w[i];
                #pragma unroll
                for (int j = 0; j < 4; ++j) {
                    const float* x = &sInv4[j][i];
                    acc[j] += ww.x * x[0] + ww.y * x[1] + ww.z * x[2] + ww.w * x[3];
                }
            }
            if (tid < 64) {
                const float bb = bq[d];
                #pragma unroll
                for (int j = 0; j < 4; ++j) sQm4[j][d] = acc[j] + bb;
            } else {
                const float bb = bk[d];
                #pragma unroll
                for (int j = 0; j < 4; ++j) kmsg[(size_t)(r0 + j) * 64 + d] = acc[j] + bb;
            }
        }
        if (tid < 192) {   // projE = equis @ Wc.T -> pTE[b][c][d][n]
            const int c = tid >> 6, e = tid & 63;
            const float* w = &Wc[e * 64];
            float acc[4] = {0.f, 0.f, 0.f, 0.f};
            for (int dd = 0; dd < 64; dd += 4) {
                f32x4_t ww = *(const f32x4_t*)&w[dd];
                #pragma unroll
                for (int j = 0; j < 4; ++j) {
                    const float* x = &sEqu4[j][c * 64 + dd];
                    acc[j] += ww.x * x[0] + ww.y * x[1] + ww.z * x[2] + ww.w * x[3];
                }
            }
            #pragma unroll
            for (int j = 0; j < 4; ++j) {
                const int bb_ = (r0 + j) >> 8, nl = (r0 + j) & 255;
                pTE[(((size_t)bb_ * 3 + c) * 64 + e) * 256 + nl] = acc[j];
            }
        }
        __syncthreads();   // sQm4 ready
        {   // qc[r][o] = sum_{d<64} W1[o][d] * qmsg[r][d]
            const float* w = &W1[tid * 256];
            float acc[4] = {0.f, 0.f, 0.f, 0.f};
            for (int d = 0; d < 64; d += 4) {
                f32x4_t ww = *(const f32x4_t*)&w[d];
                #pragma unroll
                for (int j = 0; j < 4; ++j) {
                    const float* x = &sQm4[j][d];
                    acc[j] += ww.x * x[0] + ww.y * x[1] + ww.z * x[2] + ww.w * x[3];
                }
            }
            #pragma unroll
            for (int j = 0; j < 4; ++j) qc[(size_t)(r0 + j) * 256 + tid] = acc[j];
        }
    } else if (blk < 268) {   // W1bf: 256x192, source col 64+k
        const int base = (blk - 256) * 4096;
        #pragma unroll
        for (int it = 0; it < 16; ++it) {
            const int e = base + it * 256 + tid;   // < 49152
            const int o = e / 192, k = e % 192;
            W1bf[e] = (__bf16)W1[o * 256 + 64 + k];
        }
    } else if (blk < 277) {   // W2bf reordered
        const int base = (blk - 268) * 4096;
        #pragma unroll
        for (int it = 0; it < 16; ++it) {
            const int e = base + it * 256 + tid;   // < 36864
            const int o = e >> 8, cc = e & 255;
            const int src = (o < 64) ? (72 + o) : (o < 136 ? o - 64 : -1);
            W2bf[e] = (src >= 0) ? (__bf16)W2[src * 256 + cc] : (__bf16)0.f;
        }
    }
}

// ---------------- main fused kernel: one 8-wave workgroup per (b,q) ---------
__global__ __launch_bounds__(512, 2) void semla_main(
    const float* __restrict__ equis, const float* __restrict__ edges,
    const int* __restrict__ adj,
    const __bf16* __restrict__ W1bf, const __bf16* __restrict__ W2bf,
    const float* __restrict__ qc, const float* __restrict__ kmsg,
    const float* __restrict__ pTE, const float* __restrict__ pTF,
    const float* __restrict__ b1, const float* __restrict__ b2,
    float* __restrict__ outE, float* __restrict__ outI, float* __restrict__ outEdge)
{
    const int bqid = ((blockIdx.x & 7) << 7) | (blockIdx.x >> 3);  // XCD swizzle
    const int b = bqid >> 8;
    const int tid = threadIdx.x;
    const int wave = tid >> 6, lane = tid & 63;
    const int arow = lane & 15, kgrp = lane >> 4;

    __shared__ __align__(16) __bf16 sX[KV * 192];   // 24KB X tile (K=192)
    __shared__ __align__(16) __bf16 sH[KV * 256];   // 32KB H tile
    __shared__ __align__(16) float  sS[KV * SP];    // 19KB p values
    __shared__ __align__(16) float  sB1[256];
    __shared__ __align__(16) float  sB2[144];
    __shared__ __align__(16) float  sEquiQ[192];
    __shared__ float sF[72], sL[72], sL2[72];
    __shared__ int   sAdj[KV];

    if (tid < 256) sB1[tid] = b1[tid] + qc[(size_t)bqid * 256 + tid];
    if (tid < 144) sB2[tid] = (tid < 64) ? b2[72 + tid] : (tid < 136 ? b2[tid - 64] : 0.f);
    if (tid < 192) sEquiQ[tid] = equis[(size_t)bqid * 192 + tid];

    // ---- loop-invariant weights in registers ----
    bf16x8_t w1r[6][2];                 // 32 FF cols per wave, K=192 (48 VGPR)
    #pragma unroll
    for (int ks = 0; ks < 6; ++ks)
        #pragma unroll
        for (int cf = 0; cf < 2; ++cf)
            w1r[ks][cf] = *(const bf16x8_t*)
                &W1bf[((wave << 5) + (cf << 4) + arow) * 192 + ks * 32 + (kgrp << 3)];
    bf16x8_t w2r[8];                    // wave w: W2 tile w (32 VGPR)
    #pragma unroll
    for (int ks = 0; ks < 8; ++ks)
        w2r[ks] = *(const bf16x8_t*)
            &W2bf[(((wave << 4) + arow) << 8) + ks * 32 + (kgrp << 3)];
    // wave 7's W2 tile 8 (logit ch 64-71) streamed from L2 in-loop.

    // persistent per-thread state
    float m_run = -1e30f, l_run = 0.f, l2_run = 0.f;     // waves 4-7: ch=(wave-4)*16+arow
    float m_rn2 = -1e30f, l_rn2 = 0.f, l2_rn2 = 0.f;     // wave 7, arow<8: ch=64+arow
    float accE = 0.f;                                     // tid<192: (c_e,d_e)
    float accI = 0.f;                                     // tid>=256: fidx
    const int c_e = tid >> 6, d_e = tid & 63;
    const int fidx = tid - 256, h_i = (tid - 256) >> 5;

    lds_barrier();                         // init LDS visible

    for (int kt = 0; kt < 4; ++kt) {
        const int k0 = kt * KV;
        const int kb = b * 256 + k0;

        // ---- phase 1: stage X[kt] (64 rows, +adj) and passB(kt-1) ----
        #pragma unroll
        for (int it = 0; it < 3; ++it) {
            const int g = it * 512 + tid;          // < 1536 = 64 rows x 24 chunks
            const int row = g / 24, c8 = (g % 24) << 3;
            if (c8 < 64) {
                const float* p = &kmsg[(size_t)(kb + row) * 64 + c8];
                *(bf16x8_t*)&sX[swzX(row, c8)] =
                    cvt8(*(const f32x4_t*)p, *(const f32x4_t*)(p + 4));
            } else if (c8 < 128) {
                const int d0 = c8 - 64;
                const float* ek = &equis[(size_t)(kb + row) * 192 + d0];
                f32x4_t e0a = *(const f32x4_t*)(ek),       e0b = *(const f32x4_t*)(ek + 4);
                f32x4_t e1a = *(const f32x4_t*)(ek + 64),  e1b = *(const f32x4_t*)(ek + 68);
                f32x4_t e2a = *(const f32x4_t*)(ek + 128), e2b = *(const f32x4_t*)(ek + 132);
                f32x4_t q0a = *(const f32x4_t*)&sEquiQ[d0],       q0b = *(const f32x4_t*)&sEquiQ[d0 + 4];
                f32x4_t q1a = *(const f32x4_t*)&sEquiQ[64 + d0],  q1b = *(const f32x4_t*)&sEquiQ[68 + d0];
                f32x4_t q2a = *(const f32x4_t*)&sEquiQ[128 + d0], q2b = *(const f32x4_t*)&sEquiQ[132 + d0];
                *(bf16x8_t*)&sX[swzX(row, c8)] =
                    cvt8(e0a * q0a + e1a * q1a + e2a * q2a,
                         e0b * q0b + e1b * q1b + e2b * q2b);
            } else {
                const float* p = &edges[((size_t)bqid * 256 + k0 + row) * 64 + (c8 - 128)];
                *(bf16x8_t*)&sX[swzX(row, c8)] =
                    cvt8(*(const f32x4_t*)p, *(const f32x4_t*)(p + 4));
            }
        }
        if (tid < KV) sAdj[tid] = adj[(size_t)bqid * 256 + k0 + tid];
        if (kt > 0) {
            const int k0P = k0 - KV;
            if (tid < 192) {
                float a = accE * sF[d_e];
                const float* pe = &pTE[(((size_t)b * 3 + c_e) * 64 + d_e) * 256 + k0P];
                #pragma unroll
                for (int t = 0; t < 16; ++t) {
                    f32x4_t w = *(const f32x4_t*)&pe[t * 4];
                    a += sS[(4 * t + 0) * SP + d_e] * w.x;
                    a += sS[(4 * t + 1) * SP + d_e] * w.y;
                    a += sS[(4 * t + 2) * SP + d_e] * w.z;
                    a += sS[(4 * t + 3) * SP + d_e] * w.w;
                }
                accE = a;
            }
            if (tid >= 256) {
                float a = accI * sF[64 + h_i];
                const float* pf = &pTF[((size_t)b * 256 + fidx) * 256 + k0P];
                #pragma unroll
                for (int t = 0; t < 16; ++t) {
                    f32x4_t w = *(const f32x4_t*)&pf[t * 4];
                    a += sS[(4 * t + 0) * SP + 64 + h_i] * w.x;
                    a += sS[(4 * t + 1) * SP + 64 + h_i] * w.y;
                    a += sS[(4 * t + 2) * SP + 64 + h_i] * w.z;
                    a += sS[(4 * t + 3) * SP + 64 + h_i] * w.w;
                }
                accI = a;
            }
        }
        lds_barrier();                     // (A) X staged, passB(kt-1) done

        // ---- phase 2: GEMM1 (48 MFMA, 8 indep acc) + silu -> sH ----
        f32x4_t acc1[4][2];
        {
            const f32x4_t z = {0.f, 0.f, 0.f, 0.f};
            #pragma unroll
            for (int rt = 0; rt < 4; ++rt) { acc1[rt][0] = z; acc1[rt][1] = z; }
        }
        __builtin_amdgcn_s_setprio(1);
        #pragma unroll
        for (int ks = 0; ks < 6; ++ks) {
            const int kk = ks * 32 + (kgrp << 3);
            bf16x8_t a[4];
            #pragma unroll
            for (int rt = 0; rt < 4; ++rt)
                a[rt] = *(const bf16x8_t*)&sX[swzX((rt << 4) + arow, kk)];
            #pragma unroll
            for (int rt = 0; rt < 4; ++rt) {
                acc1[rt][0] = __builtin_amdgcn_mfma_f32_16x16x32_bf16(a[rt], w1r[ks][0], acc1[rt][0], 0, 0, 0);
                acc1[rt][1] = __builtin_amdgcn_mfma_f32_16x16x32_bf16(a[rt], w1r[ks][1], acc1[rt][1], 0, 0, 0);
            }
        }
        __builtin_amdgcn_s_setprio(0);
        #pragma unroll
        for (int rt = 0; rt < 4; ++rt)
            #pragma unroll
            for (int cf = 0; cf < 2; ++cf) {
                const int ccol = (wave << 5) + (cf << 4) + arow;
                const float bb = sB1[ccol];
                #pragma unroll
                for (int j = 0; j < 4; ++j) {
                    const int row = (rt << 4) + (kgrp << 2) + j;
                    float x = acc1[rt][cf][j] + bb;
                    sH[swzH(row, ccol)] = (__bf16)(x / (1.f + __expf(-x)));
                }
            }
        lds_barrier();                     // (B) H ready

        // ---- phase 3: GEMM2 + edge stores + in-register softmax -> p ----
        f32x4_t acc2[4], acc2b[4];
        {
            const f32x4_t z = {0.f, 0.f, 0.f, 0.f};
            #pragma unroll
            for (int rt = 0; rt < 4; ++rt) { acc2[rt] = z; acc2b[rt] = z; }
        }
        __builtin_amdgcn_s_setprio(1);
        #pragma unroll
        for (int ks = 0; ks < 8; ++ks) {
            const int kk = ks * 32 + (kgrp << 3);
            bf16x8_t a[4];
            #pragma unroll
            for (int rt = 0; rt < 4; ++rt)
                a[rt] = *(const bf16x8_t*)&sH[swzH((rt << 4) + arow, kk)];
            #pragma unroll
            for (int rt = 0; rt < 4; ++rt)
                acc2[rt] = __builtin_amdgcn_mfma_f32_16x16x32_bf16(a[rt], w2r[ks], acc2[rt], 0, 0, 0);
            if (wave == 7) {
                bf16x8_t bw = *(const bf16x8_t*)&W2bf[((128 + arow) << 8) + kk];
                #pragma unroll
                for (int rt = 0; rt < 4; ++rt)
                    acc2b[rt] = __builtin_amdgcn_mfma_f32_16x16x32_bf16(a[rt], bw, acc2b[rt], 0, 0, 0);
            }
        }
        __builtin_amdgcn_s_setprio(0);
        const int col = (wave << 4) + arow;
        if (wave < 4) {
            // edge channels: direct store (left in flight across barriers)
            const float bb2 = sB2[col];
            #pragma unroll
            for (int rt = 0; rt < 4; ++rt)
                #pragma unroll
                for (int j = 0; j < 4; ++j) {
                    const int r = (rt << 4) + (kgrp << 2) + j;
                    outEdge[((size_t)bqid * 256 + k0 + r) * 64 + col] = acc2[rt][j] + bb2;
                }
        } else {
            // logit channel ch: wave holds all 64 rows across kgrp lanes
            const int ch = col - 64;
            const float bb2 = sB2[col];
            float s_[16];
            unsigned adm = 0;
            float xm = -1e30f;
            #pragma unroll
            for (int rt = 0; rt < 4; ++rt)
                #pragma unroll
                for (int j = 0; j < 4; ++j) {
                    const int r = (rt << 4) + (kgrp << 2) + j;
                    const float v = acc2[rt][j] + bb2;
                    s_[rt * 4 + j] = v;
                    if (sAdj[r]) { adm |= (1u << (rt * 4 + j)); xm = fmaxf(xm, v); }
                }
            xm = fmaxf(xm, __shfl_xor(xm, 16));
            xm = fmaxf(xm, __shfl_xor(xm, 32));
            const float mN = fmaxf(m_run, xm);
            const float f = __expf(m_run - mN);
            float s1 = 0.f, s2 = 0.f;
            #pragma unroll
            for (int rt = 0; rt < 4; ++rt)
                #pragma unroll
                for (int j = 0; j < 4; ++j) {
                    const int r = (rt << 4) + (kgrp << 2) + j;
                    const float p = ((adm >> (rt * 4 + j)) & 1u)
                                    ? __expf(s_[rt * 4 + j] - mN) : 0.f;
                    sS[r * SP + ch] = p;
                    s1 += p; s2 += p * p;
                }
            s1 += __shfl_xor(s1, 16); s1 += __shfl_xor(s1, 32);
            s2 += __shfl_xor(s2, 16); s2 += __shfl_xor(s2, 32);
            l_run = l_run * f + s1;
            l2_run = l2_run * f * f + s2;
            m_run = mN;
            if (kgrp == 0) sF[ch] = f;
        }
        if (wave == 7) {
            // tile 8: logit channels 64..71 (lanes arow<8 meaningful)
            const float bb3 = sB2[128 + (arow & 7)];
            float s_[16];
            unsigned adm = 0;
            float xm = -1e30f;
            #pragma unroll
            for (int rt = 0; rt < 4; ++rt)
                #pragma unroll
                for (int j = 0; j < 4; ++j) {
                    const int r = (rt << 4) + (kgrp << 2) + j;
                    const float v = acc2b[rt][j] + bb3;
                    s_[rt * 4 + j] = v;
                    if (sAdj[r]) { adm |= (1u << (rt * 4 + j)); xm = fmaxf(xm, v); }
                }
            xm = fmaxf(xm, __shfl_xor(xm, 16));
            xm = fmaxf(xm, __shfl_xor(xm, 32));
            const float mN = fmaxf(m_rn2, xm);
            const float f = __expf(m_rn2 - mN);
            float s1 = 0.f, s2 = 0.f;
            #pragma unroll
            for (int rt = 0; rt < 4; ++rt)
                #pragma unroll
                for (int j = 0; j < 4; ++j) {
                    const int r = (rt << 4) + (kgrp << 2) + j;
                    const float p = ((adm >> (rt * 4 + j)) & 1u)
                                    ? __expf(s_[rt * 4 + j] - mN) : 0.f;
                    if (arow < 8) sS[r * SP + 64 + arow] = p;
                    s1 += p; s2 += p * p;
                }
            s1 += __shfl_xor(s1, 16); s1 += __shfl_xor(s1, 32);
            s2 += __shfl_xor(s2, 16); s2 += __shfl_xor(s2, 32);
            l_rn2 = l_rn2 * f + s1;
            l2_rn2 = l2_rn2 * f * f + s2;
            m_rn2 = mN;
            if (kgrp == 0 && arow < 8) sF[64 + arow] = f;
        }
        lds_barrier();                     // (C) p + sF ready
    }

    // ---- final passB (kt=3 tile) ----
    {
        const int k0P = 192;
        if (tid < 192) {
            float a = accE * sF[d_e];
            const float* pe = &pTE[(((size_t)b * 3 + c_e) * 64 + d_e) * 256 + k0P];
            #pragma unroll
            for (int t = 0; t < 16; ++t) {
                f32x4_t w = *(const f32x4_t*)&pe[t * 4];
                a += sS[(4 * t + 0) * SP + d_e] * w.x;
                a += sS[(4 * t + 1) * SP + d_e] * w.y;
                a += sS[(4 * t + 2) * SP + d_e] * w.z;
                a += sS[(4 * t + 3) * SP + d_e] * w.w;
            }
            accE = a;
        }
        if (tid >= 256) {
            float a = accI * sF[64 + h_i];
            const float* pf = &pTF[((size_t)b * 256 + fidx) * 256 + k0P];
            #pragma unroll
            for (int t = 0; t < 16; ++t) {
                f32x4_t w = *(const f32x4_t*)&pf[t * 4];
                a += sS[(4 * t + 0) * SP + 64 + h_i] * w.x;
                a += sS[(4 * t + 1) * SP + 64 + h_i] * w.y;
                a += sS[(4 * t + 2) * SP + 64 + h_i] * w.z;
                a += sS[(4 * t + 3) * SP + 64 + h_i] * w.w;
            }
            accI = a;
        }
    }

    // ---- finalize: publish l, l2; write pre-GEMV outputs ----
    if (wave >= 4 && kgrp == 0) {
        const int ch = ((wave - 4) << 4) + arow;
        sL[ch] = l_run; sL2[ch] = l2_run;
        if (wave == 7 && arow < 8) { sL[64 + arow] = l_rn2; sL2[64 + arow] = l2_rn2; }
    }
    lds_barrier();
    if (tid < 192) {
        const float ll = sL[d_e];
        outE[(size_t)bqid * 192 + tid] = accE * sqrtf(sL2[d_e]) / (ll * ll);
    }
    if (tid >= 256) {
        const float ll = sL[64 + h_i];
        outI[(size_t)bqid * 256 + fidx] = accI * sqrtf(sL2[64 + h_i]) / (ll * ll);
    }
}

// ---------------- post-kernel: final Wa / Wo GEMVs, in place ----------------
__global__ __launch_bounds__(256) void semla_post(
    const float* __restrict__ Wa, const float* __restrict__ Wo,
    const float* __restrict__ bo,
    float* __restrict__ outE, float* __restrict__ outI)
{
    __shared__ __align__(16) float hE[4][192];
    __shared__ __align__(16) float hI[4][256];
    const int blk = blockIdx.x, tid = threadIdx.x;
    const int r0 = blk * 4;
    #pragma unroll
    for (int r = 0; r < 4; ++r) {
        if (tid < 192) hE[r][tid] = outE[(size_t)(r0 + r) * 192 + tid];
        hI[r][tid] = outI[(size_t)(r0 + r) * 256 + tid];
    }
    __syncthreads();
    if (tid < 192) {                        // equi_updates = hE @ Wa^T
        const int c = tid >> 6, e = tid & 63;
        float wa[64];
        #pragma unroll
        for (int d = 0; d < 64; d += 4) {
            f32x4_t w = *(const f32x4_t*)&Wa[e * 64 + d];
            wa[d] = w.x; wa[d + 1] = w.y; wa[d + 2] = w.z; wa[d + 3] = w.w;
        }
        #pragma unroll
        for (int r = 0; r < 4; ++r) {
            float s = 0.f;
            #pragma unroll
            for (int d = 0; d < 64; ++d) s += hE[r][c * 64 + d] * wa[d];
            outE[((size_t)(r0 + r) * 3 + c) * 64 + e] = s;
        }
    }
    {                                       // inv_updates = hI @ Wo^T + bo
        const float bb = bo[tid];
        const float* wo = &Wo[tid * 256];
        #pragma unroll
        for (int r = 0; r < 4; ++r) {
            float s = 0.f;
            for (int i = 0; i < 256; i += 4) {
                f32x4_t w = *(const f32x4_t*)&wo[i];
                s += w.x * hI[r][i] + w.y * hI[r][i + 1]
                   + w.z * hI[r][i + 2] + w.w * hI[r][i + 3];
            }
            outI[(size_t)(r0 + r) * 256 + tid] = s + bb;
        }
    }
}

extern "C" void kernel_launch(void* const* d_in, const int* in_sizes, int n_in,
                              void* d_out, int out_size, void* d_ws, size_t ws_size,
                              hipStream_t stream) {
    (void)in_sizes; (void)n_in; (void)out_size; (void)ws_size;
    const float* equis = (const float*)d_in[0];
    const float* invs  = (const float*)d_in[1];
    const float* edges = (const float*)d_in[2];
    const int*   adj   = (const int*)d_in[3];
    const float* Wq = (const float*)d_in[4];
    const float* bq = (const float*)d_in[5];
    const float* Wk = (const float*)d_in[6];
    const float* bk = (const float*)d_in[7];
    const float* W1 = (const float*)d_in[8];
    const float* b1 = (const float*)d_in[9];
    const float* W2 = (const float*)d_in[10];
    const float* b2 = (const float*)d_in[11];
    const float* Wc = (const float*)d_in[12];
    const float* Wa = (const float*)d_in[13];
    const float* Wi = (const float*)d_in[14];
    const float* bi = (const float*)d_in[15];
    const float* Wo = (const float*)d_in[16];
    const float* bo = (const float*)d_in[17];

    float* out = (float*)d_out;
    float* outE    = out;                  // (B,N,3,64)  = 196608
    float* outI    = out + 196608;         // (B,N,256)   = 262144
    float* outEdge = out + 458752;         // (B,N,N,64)  = 16777216

    char* ws = (char*)d_ws;
    __bf16* W1bf = (__bf16*)(ws);                    //  98304 B (256x192)
    __bf16* W2bf = (__bf16*)(ws + 98304);            //  73728 B (144x256)
    float* qc    = (float*)(ws + 172032);            // 1048576 B
    float* kmsg  = (float*)(ws + 1220608);           //  262144 B
    float* pTE   = (float*)(ws + 1482752);           //  786432 B
    float* pTF   = (float*)(ws + 2269184);           // 1048576 B -> 3317760 total

    semla_pre<<<277, 256, 0, stream>>>(invs, equis, Wq, bq, Wk, bk, Wc, Wi, bi,
                                       W1, W2, W1bf, W2bf, qc, kmsg, pTE, pTF);
    semla_main<<<1024, 512, 0, stream>>>(equis, edges, adj, W1bf, W2bf, qc, kmsg,
                                         pTE, pTF, b1, b2,
                                         outE, outI, outEdge);
    semla_post<<<256, 256, 0, stream>>>(Wa, Wo, bo, outE, outI);
}

// Round 19
// 296.986 us; speedup vs baseline: 1.1193x; 1.1193x over previous
//
#include <hip/hip_runtime.h>
#include <hip/hip_bf16.h>
#include <cstdint>

// SemlaLayer fused forward for MI355X (gfx950).
// R19 = R17 main (best: 270us) + re-gridded pre (533 blocks, 2 rows each)
// and post (512 blocks, 2 rows each) to halve their single-round critical
// paths. Main kernel unchanged from R17.

typedef __bf16 bf16x8_t __attribute__((ext_vector_type(8)));
typedef float  f32x4_t  __attribute__((ext_vector_type(4)));

#define SP 76   // sS pitch in floats
#define KV 32   // k-tile rows

__device__ __forceinline__ int swzX(int row, int col) {   // pitch 192
    return row * 192 + (col ^ ((row & 7) << 3));
}
__device__ __forceinline__ int swzH(int row, int col) {   // pitch 256
    return (row << 8) + (col ^ ((row & 7) << 3));
}

__device__ __forceinline__ bf16x8_t cvt8(f32x4_t a, f32x4_t b) {
    bf16x8_t r;
    r[0] = (__bf16)a.x; r[1] = (__bf16)a.y; r[2] = (__bf16)a.z; r[3] = (__bf16)a.w;
    r[4] = (__bf16)b.x; r[5] = (__bf16)b.y; r[6] = (__bf16)b.z; r[7] = (__bf16)b.w;
    return r;
}

__device__ __forceinline__ void lds_barrier() {
    asm volatile("s_waitcnt lgkmcnt(0)" ::: "memory");
    __builtin_amdgcn_s_barrier();
    asm volatile("" ::: "memory");
}

// ---------------- pre-kernel ----------------
// blocks 0..511  : 2 (b,n) rows each -> kmsg, pTE, pTF (transposed), qc
// blocks 512..523: W1bf (256x192, W1 cols 64..255)
// blocks 524..532: W2bf (144x256, rows reordered: edge(72..135)|logit(0..71)|pad)
__global__ __launch_bounds__(256) void semla_pre(
    const float* __restrict__ invs, const float* __restrict__ equis,
    const float* __restrict__ Wq, const float* __restrict__ bq,
    const float* __restrict__ Wk, const float* __restrict__ bk,
    const float* __restrict__ Wc, const float* __restrict__ Wi, const float* __restrict__ bi,
    const float* __restrict__ W1, const float* __restrict__ W2,
    __bf16* __restrict__ W1bf, __bf16* __restrict__ W2bf,
    float* __restrict__ qc, float* __restrict__ kmsg,
    float* __restrict__ pTE, float* __restrict__ pTF)
{
    const int blk = blockIdx.x, tid = threadIdx.x;
    if (blk < 512) {
        const int r0 = blk * 2;
        __shared__ __align__(16) float sInv2[2][256];
        __shared__ __align__(16) float sEqu2[2][192];
        __shared__ __align__(16) float sQm2[2][64];
        #pragma unroll
        for (int j = 0; j < 2; ++j) {
            sInv2[j][tid] = invs[(size_t)(r0 + j) * 256 + tid];
            if (tid < 192) sEqu2[j][tid] = equis[(size_t)(r0 + j) * 192 + tid];
        }
        __syncthreads();
        {   // projF = invs @ Wi.T + bi  -> pTF[b][f][n]
            float acc[2] = {0.f, 0.f};
            const float* w = &Wi[tid * 256];
            for (int i = 0; i < 256; i += 4) {
                f32x4_t ww = *(const f32x4_t*)&w[i];
                #pragma unroll
                for (int j = 0; j < 2; ++j) {
                    const float* x = &sInv2[j][i];
                    acc[j] += ww.x * x[0] + ww.y * x[1] + ww.z * x[2] + ww.w * x[3];
                }
            }
            const float bb = bi[tid];
            #pragma unroll
            for (int j = 0; j < 2; ++j) {
                const int bb_ = (r0 + j) >> 8, nl = (r0 + j) & 255;
                pTF[((size_t)bb_ * 256 + tid) * 256 + nl] = acc[j] + bb;
            }
        }
        if (tid < 128) {   // qmsg (to LDS) / kmsg (to global)
            const int d = tid & 63;
            const float* w = (tid < 64) ? &Wq[d * 256] : &Wk[d * 256];
            float acc[2] = {0.f, 0.f};
            for (int i = 0; i < 256; i += 4) {
                f32x4_t ww = *(const f32x4_t*)&w[i];
                #pragma unroll
                for (int j = 0; j < 2; ++j) {
                    const float* x = &sInv2[j][i];
                    acc[j] += ww.x * x[0] + ww.y * x[1] + ww.z * x[2] + ww.w * x[3];
                }
            }
            if (tid < 64) {
                const float bb = bq[d];
                #pragma unroll
                for (int j = 0; j < 2; ++j) sQm2[j][d] = acc[j] + bb;
            } else {
                const float bb = bk[d];
                #pragma unroll
                for (int j = 0; j < 2; ++j) kmsg[(size_t)(r0 + j) * 64 + d] = acc[j] + bb;
            }
        }
        if (tid < 192) {   // projE = equis @ Wc.T -> pTE[b][c][d][n]
            const int c = tid >> 6, e = tid & 63;
            const float* w = &Wc[e * 64];
            float acc[2] = {0.f, 0.f};
            for (int dd = 0; dd < 64; dd += 4) {
                f32x4_t ww = *(const f32x4_t*)&w[dd];
                #pragma unroll
                for (int j = 0; j < 2; ++j) {
                    const float* x = &sEqu2[j][c * 64 + dd];
                    acc[j] += ww.x * x[0] + ww.y * x[1] + ww.z * x[2] + ww.w * x[3];
                }
            }
            #pragma unroll
            for (int j = 0; j < 2; ++j) {
                const int bb_ = (r0 + j) >> 8, nl = (r0 + j) & 255;
                pTE[(((size_t)bb_ * 3 + c) * 64 + e) * 256 + nl] = acc[j];
            }
        }
        __syncthreads();   // sQm2 ready
        {   // qc[r][o] = sum_{d<64} W1[o][d] * qmsg[r][d]
            const float* w = &W1[tid * 256];
            float acc[2] = {0.f, 0.f};
            for (int d = 0; d < 64; d += 4) {
                f32x4_t ww = *(const f32x4_t*)&w[d];
                #pragma unroll
                for (int j = 0; j < 2; ++j) {
                    const float* x = &sQm2[j][d];
                    acc[j] += ww.x * x[0] + ww.y * x[1] + ww.z * x[2] + ww.w * x[3];
                }
            }
            #pragma unroll
            for (int j = 0; j < 2; ++j) qc[(size_t)(r0 + j) * 256 + tid] = acc[j];
        }
    } else if (blk < 524) {   // W1bf: 256x192, source col 64+k
        const int base = (blk - 512) * 4096;
        #pragma unroll
        for (int it = 0; it < 16; ++it) {
            const int e = base + it * 256 + tid;   // < 49152
            const int o = e / 192, k = e % 192;
            W1bf[e] = (__bf16)W1[o * 256 + 64 + k];
        }
    } else if (blk < 533) {   // W2bf reordered
        const int base = (blk - 524) * 4096;
        #pragma unroll
        for (int it = 0; it < 16; ++it) {
            const int e = base + it * 256 + tid;   // < 36864
            const int o = e >> 8, cc = e & 255;
            const int src = (o < 64) ? (72 + o) : (o < 136 ? o - 64 : -1);
            W2bf[e] = (src >= 0) ? (__bf16)W2[src * 256 + cc] : (__bf16)0.f;
        }
    }
}

// ---------------- main fused kernel: one 8-wave workgroup per (b,q) ---------
__global__ __launch_bounds__(512, 2) void semla_main(
    const float* __restrict__ equis, const float* __restrict__ edges,
    const int* __restrict__ adj,
    const __bf16* __restrict__ W1bf, const __bf16* __restrict__ W2bf,
    const float* __restrict__ qc, const float* __restrict__ kmsg,
    const float* __restrict__ pTE, const float* __restrict__ pTF,
    const float* __restrict__ b1, const float* __restrict__ b2,
    float* __restrict__ outE, float* __restrict__ outI, float* __restrict__ outEdge)
{
    const int bqid = ((blockIdx.x & 7) << 7) | (blockIdx.x >> 3);  // XCD swizzle
    const int b = bqid >> 8;
    const int tid = threadIdx.x;
    const int wave = tid >> 6, lane = tid & 63;
    const int arow = lane & 15, kgrp = lane >> 4;

    __shared__ __align__(16) __bf16 sX[KV * 192];   // 12KB X tile (K=192)
    __shared__ __align__(16) __bf16 sH[KV * 256];   // 16KB H tile
    __shared__ __align__(16) float  sS[KV * SP];    // p values
    __shared__ __align__(16) float  sB1[256];
    __shared__ __align__(16) float  sB2[144];
    __shared__ __align__(16) float  sEquiQ[192];
    __shared__ float sF[72], sL[72], sL2[72];
    __shared__ int   sAdj[KV];

    if (tid < 256) sB1[tid] = b1[tid] + qc[(size_t)bqid * 256 + tid];
    if (tid < 144) sB2[tid] = (tid < 64) ? b2[72 + tid] : (tid < 136 ? b2[tid - 64] : 0.f);
    if (tid < 192) sEquiQ[tid] = equis[(size_t)bqid * 192 + tid];

    // ---- loop-invariant weights in registers ----
    bf16x8_t w1r[6][2];                 // 32 FF cols per wave, K=192
    #pragma unroll
    for (int ks = 0; ks < 6; ++ks)
        #pragma unroll
        for (int cf = 0; cf < 2; ++cf)
            w1r[ks][cf] = *(const bf16x8_t*)
                &W1bf[((wave << 5) + (cf << 4) + arow) * 192 + ks * 32 + (kgrp << 3)];
    bf16x8_t w2r[8], w2r2[8];           // wave w: tile w; wave 7 also tile 8
    #pragma unroll
    for (int ks = 0; ks < 8; ++ks)
        w2r[ks] = *(const bf16x8_t*)
            &W2bf[(((wave << 4) + arow) << 8) + ks * 32 + (kgrp << 3)];
    if (wave == 7) {
        #pragma unroll
        for (int ks = 0; ks < 8; ++ks)
            w2r2[ks] = *(const bf16x8_t*)
                &W2bf[((128 + arow) << 8) + ks * 32 + (kgrp << 3)];
    }

    // persistent per-thread state
    float m_run = -1e30f, l_run = 0.f, l2_run = 0.f;     // waves 4-7: ch=(wave-4)*16+arow
    float m_rn2 = -1e30f, l_rn2 = 0.f, l2_rn2 = 0.f;     // wave 7, arow<8: ch=64+arow
    float accE = 0.f;                                     // tid<192: (c_e,d_e)
    float accI = 0.f;                                     // tid>=256: fidx
    const int c_e = tid >> 6, d_e = tid & 63;
    const int fidx = tid - 256, h_i = (tid - 256) >> 5;

    lds_barrier();                         // init LDS visible

    for (int kt = 0; kt < 8; ++kt) {
        const int k0 = kt * KV;
        const int kb = b * 256 + k0;

        // ---- phase 1: stage X[kt] (+adj) and passB(kt-1) ----
        #pragma unroll
        for (int gi = 0; gi < 2; ++gi) {
            const int g = (gi == 0) ? tid : 512 + tid;
            if (gi == 1 && tid >= 256) continue;
            const int row = g / 24, c8 = (g % 24) << 3;
            if (c8 < 64) {
                const float* p = &kmsg[(size_t)(kb + row) * 64 + c8];
                *(bf16x8_t*)&sX[swzX(row, c8)] =
                    cvt8(*(const f32x4_t*)p, *(const f32x4_t*)(p + 4));
            } else if (c8 < 128) {
                const int d0 = c8 - 64;
                const float* ek = &equis[(size_t)(kb + row) * 192 + d0];
                f32x4_t e0a = *(const f32x4_t*)(ek),       e0b = *(const f32x4_t*)(ek + 4);
                f32x4_t e1a = *(const f32x4_t*)(ek + 64),  e1b = *(const f32x4_t*)(ek + 68);
                f32x4_t e2a = *(const f32x4_t*)(ek + 128), e2b = *(const f32x4_t*)(ek + 132);
                f32x4_t q0a = *(const f32x4_t*)&sEquiQ[d0],       q0b = *(const f32x4_t*)&sEquiQ[d0 + 4];
                f32x4_t q1a = *(const f32x4_t*)&sEquiQ[64 + d0],  q1b = *(const f32x4_t*)&sEquiQ[68 + d0];
                f32x4_t q2a = *(const f32x4_t*)&sEquiQ[128 + d0], q2b = *(const f32x4_t*)&sEquiQ[132 + d0];
                *(bf16x8_t*)&sX[swzX(row, c8)] =
                    cvt8(e0a * q0a + e1a * q1a + e2a * q2a,
                         e0b * q0b + e1b * q1b + e2b * q2b);
            } else {
                const float* p = &edges[((size_t)bqid * 256 + k0 + row) * 64 + (c8 - 128)];
                *(bf16x8_t*)&sX[swzX(row, c8)] =
                    cvt8(*(const f32x4_t*)p, *(const f32x4_t*)(p + 4));
            }
        }
        if (tid < KV) sAdj[tid] = adj[(size_t)bqid * 256 + k0 + tid];
        if (kt > 0) {
            const int k0P = k0 - KV;
            if (tid < 192) {
                float a = accE * sF[d_e];
                const float* pe = &pTE[(((size_t)b * 3 + c_e) * 64 + d_e) * 256 + k0P];
                #pragma unroll
                for (int t = 0; t < 8; ++t) {
                    f32x4_t w = *(const f32x4_t*)&pe[t * 4];
                    a += sS[(4 * t + 0) * SP + d_e] * w.x;
                    a += sS[(4 * t + 1) * SP + d_e] * w.y;
                    a += sS[(4 * t + 2) * SP + d_e] * w.z;
                    a += sS[(4 * t + 3) * SP + d_e] * w.w;
                }
                accE = a;
            }
            if (tid >= 256) {
                float a = accI * sF[64 + h_i];
                const float* pf = &pTF[((size_t)b * 256 + fidx) * 256 + k0P];
                #pragma unroll
                for (int t = 0; t < 8; ++t) {
                    f32x4_t w = *(const f32x4_t*)&pf[t * 4];
                    a += sS[(4 * t + 0) * SP + 64 + h_i] * w.x;
                    a += sS[(4 * t + 1) * SP + 64 + h_i] * w.y;
                    a += sS[(4 * t + 2) * SP + 64 + h_i] * w.z;
                    a += sS[(4 * t + 3) * SP + 64 + h_i] * w.w;
                }
                accI = a;
            }
        }
        lds_barrier();                     // (A) X staged, passB(kt-1) done

        // ---- phase 2: GEMM1 (K=192, W1 in regs) + silu -> sH ----
        f32x4_t acc1[2][2];
        {
            const f32x4_t z = {0.f, 0.f, 0.f, 0.f};
            acc1[0][0] = z; acc1[0][1] = z; acc1[1][0] = z; acc1[1][1] = z;
        }
        __builtin_amdgcn_s_setprio(1);
        #pragma unroll
        for (int ks = 0; ks < 6; ++ks) {
            const int kk = ks * 32 + (kgrp << 3);
            bf16x8_t a0 = *(const bf16x8_t*)&sX[swzX(arow, kk)];
            bf16x8_t a1 = *(const bf16x8_t*)&sX[swzX(16 + arow, kk)];
            acc1[0][0] = __builtin_amdgcn_mfma_f32_16x16x32_bf16(a0, w1r[ks][0], acc1[0][0], 0, 0, 0);
            acc1[0][1] = __builtin_amdgcn_mfma_f32_16x16x32_bf16(a0, w1r[ks][1], acc1[0][1], 0, 0, 0);
            acc1[1][0] = __builtin_amdgcn_mfma_f32_16x16x32_bf16(a1, w1r[ks][0], acc1[1][0], 0, 0, 0);
            acc1[1][1] = __builtin_amdgcn_mfma_f32_16x16x32_bf16(a1, w1r[ks][1], acc1[1][1], 0, 0, 0);
        }
        __builtin_amdgcn_s_setprio(0);
        #pragma unroll
        for (int rt = 0; rt < 2; ++rt)
            #pragma unroll
            for (int cf = 0; cf < 2; ++cf) {
                const int ccol = (wave << 5) + (cf << 4) + arow;
                const float bb = sB1[ccol];
                #pragma unroll
                for (int j = 0; j < 4; ++j) {
                    const int row = (rt << 4) + (kgrp << 2) + j;
                    float x = acc1[rt][cf][j] + bb;
                    sH[swzH(row, ccol)] = (__bf16)(x / (1.f + __expf(-x)));
                }
            }
        lds_barrier();                     // (B) H ready

        // ---- phase 3: GEMM2 + edge stores + IN-REGISTER softmax -> p ----
        f32x4_t acc2[2], acc2b[2];
        {
            const f32x4_t z = {0.f, 0.f, 0.f, 0.f};
            acc2[0] = z; acc2[1] = z; acc2b[0] = z; acc2b[1] = z;
        }
        __builtin_amdgcn_s_setprio(1);
        #pragma unroll
        for (int ks = 0; ks < 8; ++ks) {
            const int kk = ks * 32 + (kgrp << 3);
            bf16x8_t a0 = *(const bf16x8_t*)&sH[swzH(arow, kk)];
            bf16x8_t a1 = *(const bf16x8_t*)&sH[swzH(16 + arow, kk)];
            acc2[0] = __builtin_amdgcn_mfma_f32_16x16x32_bf16(a0, w2r[ks], acc2[0], 0, 0, 0);
            acc2[1] = __builtin_amdgcn_mfma_f32_16x16x32_bf16(a1, w2r[ks], acc2[1], 0, 0, 0);
            if (wave == 7) {
                acc2b[0] = __builtin_amdgcn_mfma_f32_16x16x32_bf16(a0, w2r2[ks], acc2b[0], 0, 0, 0);
                acc2b[1] = __builtin_amdgcn_mfma_f32_16x16x32_bf16(a1, w2r2[ks], acc2b[1], 0, 0, 0);
            }
        }
        __builtin_amdgcn_s_setprio(0);
        const int col = (wave << 4) + arow;
        if (wave < 4) {
            // edge channels: direct store (left in flight across barriers)
            const float bb2 = sB2[col];
            #pragma unroll
            for (int rt = 0; rt < 2; ++rt)
                #pragma unroll
                for (int j = 0; j < 4; ++j) {
                    const int r = (rt << 4) + (kgrp << 2) + j;
                    outEdge[((size_t)bqid * 256 + k0 + r) * 64 + col] = acc2[rt][j] + bb2;
                }
        } else {
            // logit channel ch: this wave holds ALL 32 rows across kgrp lanes
            const int ch = col - 64;
            const float bb2 = sB2[col];
            float s_[8]; int ad_[8];
            float xm = -1e30f;
            #pragma unroll
            for (int rt = 0; rt < 2; ++rt)
                #pragma unroll
                for (int j = 0; j < 4; ++j) {
                    const int r = (rt << 4) + (kgrp << 2) + j;
                    const float v = acc2[rt][j] + bb2;
                    s_[rt * 4 + j] = v;
                    ad_[rt * 4 + j] = sAdj[r];
                    if (ad_[rt * 4 + j]) xm = fmaxf(xm, v);
                }
            xm = fmaxf(xm, __shfl_xor(xm, 16));
            xm = fmaxf(xm, __shfl_xor(xm, 32));
            const float mN = fmaxf(m_run, xm);
            const float f = __expf(m_run - mN);
            float s1 = 0.f, s2 = 0.f;
            #pragma unroll
            for (int rt = 0; rt < 2; ++rt)
                #pragma unroll
                for (int j = 0; j < 4; ++j) {
                    const int r = (rt << 4) + (kgrp << 2) + j;
                    const float p = ad_[rt * 4 + j] ? __expf(s_[rt * 4 + j] - mN) : 0.f;
                    sS[r * SP + ch] = p;
                    s1 += p; s2 += p * p;
                }
            s1 += __shfl_xor(s1, 16); s1 += __shfl_xor(s1, 32);
            s2 += __shfl_xor(s2, 16); s2 += __shfl_xor(s2, 32);
            l_run = l_run * f + s1;
            l2_run = l2_run * f * f + s2;
            m_run = mN;
            if (kgrp == 0) sF[ch] = f;
        }
        if (wave == 7) {
            // tile 8: logit channels 64..71 (lanes arow<8 meaningful)
            const float bb3 = sB2[128 + (arow & 7)];
            float s_[8]; int ad_[8];
            float xm = -1e30f;
            #pragma unroll
            for (int rt = 0; rt < 2; ++rt)
                #pragma unroll
                for (int j = 0; j < 4; ++j) {
                    const int r = (rt << 4) + (kgrp << 2) + j;
                    const float v = acc2b[rt][j] + bb3;
                    s_[rt * 4 + j] = v;
                    ad_[rt * 4 + j] = sAdj[r];
                    if (ad_[rt * 4 + j]) xm = fmaxf(xm, v);
                }
            xm = fmaxf(xm, __shfl_xor(xm, 16));
            xm = fmaxf(xm, __shfl_xor(xm, 32));
            const float mN = fmaxf(m_rn2, xm);
            const float f = __expf(m_rn2 - mN);
            float s1 = 0.f, s2 = 0.f;
            #pragma unroll
            for (int rt = 0; rt < 2; ++rt)
                #pragma unroll
                for (int j = 0; j < 4; ++j) {
                    const int r = (rt << 4) + (kgrp << 2) + j;
                    const float p = ad_[rt * 4 + j] ? __expf(s_[rt * 4 + j] - mN) : 0.f;
                    if (arow < 8) sS[r * SP + 64 + arow] = p;
                    s1 += p; s2 += p * p;
                }
            s1 += __shfl_xor(s1, 16); s1 += __shfl_xor(s1, 32);
            s2 += __shfl_xor(s2, 16); s2 += __shfl_xor(s2, 32);
            l_rn2 = l_rn2 * f + s1;
            l2_rn2 = l2_rn2 * f * f + s2;
            m_rn2 = mN;
            if (kgrp == 0 && arow < 8) sF[64 + arow] = f;
        }
        lds_barrier();                     // (C) p + sF ready
    }

    // ---- final passB (kt=7 tile) ----
    {
        const int k0P = 224;
        if (tid < 192) {
            float a = accE * sF[d_e];
            const float* pe = &pTE[(((size_t)b * 3 + c_e) * 64 + d_e) * 256 + k0P];
            #pragma unroll
            for (int t = 0; t < 8; ++t) {
                f32x4_t w = *(const f32x4_t*)&pe[t * 4];
                a += sS[(4 * t + 0) * SP + d_e] * w.x;
                a += sS[(4 * t + 1) * SP + d_e] * w.y;
                a += sS[(4 * t + 2) * SP + d_e] * w.z;
                a += sS[(4 * t + 3) * SP + d_e] * w.w;
            }
            accE = a;
        }
        if (tid >= 256) {
            float a = accI * sF[64 + h_i];
            const float* pf = &pTF[((size_t)b * 256 + fidx) * 256 + k0P];
            #pragma unroll
            for (int t = 0; t < 8; ++t) {
                f32x4_t w = *(const f32x4_t*)&pf[t * 4];
                a += sS[(4 * t + 0) * SP + 64 + h_i] * w.x;
                a += sS[(4 * t + 1) * SP + 64 + h_i] * w.y;
                a += sS[(4 * t + 2) * SP + 64 + h_i] * w.z;
                a += sS[(4 * t + 3) * SP + 64 + h_i] * w.w;
            }
            accI = a;
        }
    }

    // ---- finalize: publish l, l2; write pre-GEMV outputs ----
    if (wave >= 4 && kgrp == 0) {
        const int ch = ((wave - 4) << 4) + arow;
        sL[ch] = l_run; sL2[ch] = l2_run;
        if (wave == 7 && arow < 8) { sL[64 + arow] = l_rn2; sL2[64 + arow] = l2_rn2; }
    }
    lds_barrier();
    if (tid < 192) {
        const float ll = sL[d_e];
        outE[(size_t)bqid * 192 + tid] = accE * sqrtf(sL2[d_e]) / (ll * ll);
    }
    if (tid >= 256) {
        const float ll = sL[64 + h_i];
        outI[(size_t)bqid * 256 + fidx] = accI * sqrtf(sL2[64 + h_i]) / (ll * ll);
    }
}

// ---------------- post-kernel: final Wa / Wo GEMVs, in place ----------------
__global__ __launch_bounds__(256) void semla_post(
    const float* __restrict__ Wa, const float* __restrict__ Wo,
    const float* __restrict__ bo,
    float* __restrict__ outE, float* __restrict__ outI)
{
    __shared__ __align__(16) float hE[2][192];
    __shared__ __align__(16) float hI[2][256];
    const int blk = blockIdx.x, tid = threadIdx.x;
    const int r0 = blk * 2;
    #pragma unroll
    for (int r = 0; r < 2; ++r) {
        if (tid < 192) hE[r][tid] = outE[(size_t)(r0 + r) * 192 + tid];
        hI[r][tid] = outI[(size_t)(r0 + r) * 256 + tid];
    }
    __syncthreads();
    if (tid < 192) {                        // equi_updates = hE @ Wa^T
        const int c = tid >> 6, e = tid & 63;
        float wa[64];
        #pragma unroll
        for (int d = 0; d < 64; d += 4) {
            f32x4_t w = *(const f32x4_t*)&Wa[e * 64 + d];
            wa[d] = w.x; wa[d + 1] = w.y; wa[d + 2] = w.z; wa[d + 3] = w.w;
        }
        #pragma unroll
        for (int r = 0; r < 2; ++r) {
            float s = 0.f;
            #pragma unroll
            for (int d = 0; d < 64; ++d) s += hE[r][c * 64 + d] * wa[d];
            outE[((size_t)(r0 + r) * 3 + c) * 64 + e] = s;
        }
    }
    {                                       // inv_updates = hI @ Wo^T + bo
        const float bb = bo[tid];
        const float* wo = &Wo[tid * 256];
        #pragma unroll
        for (int r = 0; r < 2; ++r) {
            float s = 0.f;
            for (int i = 0; i < 256; i += 4) {
                f32x4_t w = *(const f32x4_t*)&wo[i];
                s += w.x * hI[r][i] + w.y * hI[r][i + 1]
                   + w.z * hI[r][i + 2] + w.w * hI[r][i + 3];
            }
            outI[(size_t)(r0 + r) * 256 + tid] = s + bb;
        }
    }
}

extern "C" void kernel_launch(void* const* d_in, const int* in_sizes, int n_in,
                              void* d_out, int out_size, void* d_ws, size_t ws_size,
                              hipStream_t stream) {
    (void)in_sizes; (void)n_in; (void)out_size; (void)ws_size;
    const float* equis = (const float*)d_in[0];
    const float* invs  = (const float*)d_in[1];
    const float* edges = (const float*)d_in[2];
    const int*   adj   = (const int*)d_in[3];
    const float* Wq = (const float*)d_in[4];
    const float* bq = (const float*)d_in[5];
    const float* Wk = (const float*)d_in[6];
    const float* bk = (const float*)d_in[7];
    const float* W1 = (const float*)d_in[8];
    const float* b1 = (const float*)d_in[9];
    const float* W2 = (const float*)d_in[10];
    const float* b2 = (const float*)d_in[11];
    const float* Wc = (const float*)d_in[12];
    const float* Wa = (const float*)d_in[13];
    const float* Wi = (const float*)d_in[14];
    const float* bi = (const float*)d_in[15];
    const float* Wo = (const float*)d_in[16];
    const float* bo = (const float*)d_in[17];

    float* out = (float*)d_out;
    float* outE    = out;                  // (B,N,3,64)  = 196608
    float* outI    = out + 196608;         // (B,N,256)   = 262144
    float* outEdge = out + 458752;         // (B,N,N,64)  = 16777216

    char* ws = (char*)d_ws;
    __bf16* W1bf = (__bf16*)(ws);                    //  98304 B (256x192)
    __bf16* W2bf = (__bf16*)(ws + 98304);            //  73728 B (144x256)
    float* qc    = (float*)(ws + 172032);            // 1048576 B
    float* kmsg  = (float*)(ws + 1220608);           //  262144 B
    float* pTE   = (float*)(ws + 1482752);           //  786432 B
    float* pTF   = (float*)(ws + 2269184);           // 1048576 B -> 3317760 total

    semla_pre<<<533, 256, 0, stream>>>(invs, equis, Wq, bq, Wk, bk, Wc, Wi, bi,
                                       W1, W2, W1bf, W2bf, qc, kmsg, pTE, pTF);
    semla_main<<<1024, 512, 0, stream>>>(equis, edges, adj, W1bf, W2bf, qc, kmsg,
                                         pTE, pTF, b1, b2,
                                         outE, outI, outEdge);
    semla_post<<<512, 256, 0, stream>>>(Wa, Wo, bo, outE, outI);
}